// Round 17
// baseline (332.417 us; speedup 1.0000x reference)
//
#include <hip/hip_runtime.h>
#include <hip/hip_bf16.h>

#define TPB 256
#define TPB1 512        // threads for phase1_sort (1 bucket bin per thread)
#define NB 512          // partition buckets
#define MAXW 256        // max nodes per bucket (ceil(n/NB) <= MAXW)
#define P1K 16          // edges per thread per chunk (TPB1*P1K = 8192)
#define CH (TPB1*P1K)   // 8192 edges per chunk
#define MAXB 13312      // max edges/bucket staged in LDS (52KB); < 2^14 for packing
#define MAXCHUNK 1024
#define NSHADOW 8       // fallback path
#define NTEAM 8
#define TEAMS_PER 256

// inclusive block scan over 512 threads via wave-shfl (2 barriers); ws8 = LDS[8]
__device__ __forceinline__ int block_scan_incl_512(int v, int* ws8){
  int lane = threadIdx.x & 63, wid = threadIdx.x >> 6;
  #pragma unroll
  for(int off=1; off<64; off<<=1){
    int u = __shfl_up(v, off, 64);
    if(lane >= off) v += u;
  }
  if(lane == 63) ws8[wid] = v;
  __syncthreads();
  if(wid == 0){
    int s = (lane < 8) ? ws8[lane] : 0;
    #pragma unroll
    for(int off=1; off<8; off<<=1){
      int u = __shfl_up(s, off, 64);
      if(lane >= off) s += u;
    }
    if(lane < 8) ws8[lane] = s;
  }
  __syncthreads();
  return v + ((wid > 0) ? ws8[wid-1] : 0);
}

// ============================ chunk-sorted build ============================

__global__ void k_zero512(int* __restrict__ bsize){
  bsize[threadIdx.x] = 0;
}

// per chunk: LDS counting sort by dst-bucket, single atomic pass, per-edge state
// packed into ONE register: meta = (r<<17)|(b<<8)|dstLocal. src read at scatter.
__global__ __launch_bounds__(TPB1)
void k_phase1_sort(const int* __restrict__ src, const int* __restrict__ dst,
                   int E, int n, int nchunk,
                   unsigned* __restrict__ temp, int* __restrict__ bhist,
                   int* __restrict__ bsize, int sbits){
  __shared__ int lcur[2*NB];
  __shared__ int ws8[8];
  __shared__ unsigned stage[CH];
  int t = threadIdx.x;
  int wid = t >> 6;
  int shbase = (wid & 1) * NB;
  for(int c = blockIdx.x; c < nchunk; c += gridDim.x){
    int cb = c * CH;
    int ce = E - cb; if(ce > CH) ce = CH;
    lcur[t] = 0; lcur[t + NB] = 0;
    __syncthreads();
    unsigned meta[P1K];
    #pragma unroll
    for(int i = 0; i < P1K; i++){
      int e = cb + i*TPB1 + t;
      if(e < E){
        int d = dst[e];
        int b = (int)(((long long)d * NB) / n);
        int lo = (int)(((long long)n * b + NB - 1) / NB);
        int r = atomicAdd(&lcur[shbase + b], 1);
        meta[i] = ((unsigned)r << 17) | ((unsigned)b << 8) | (unsigned)(d - lo);
      } else meta[i] = 0xFFFFFFFFu;
    }
    __syncthreads();
    int cnt0 = lcur[t], cnt1 = lcur[NB + t];
    int tot = cnt0 + cnt1;
    int incl = block_scan_incl_512(tot, ws8);
    int base = incl - tot;
    bhist[(size_t)c*NB + t] = base;
    if(tot > 0) atomicAdd(&bsize[t], tot);
    lcur[t]      = base;          // shadow-0 base
    lcur[NB + t] = base + cnt0;   // shadow-1 base
    __syncthreads();
    #pragma unroll
    for(int i = 0; i < P1K; i++){
      if(meta[i] != 0xFFFFFFFFu){
        int e = cb + i*TPB1 + t;
        unsigned m = meta[i];
        int b = (int)((m >> 8) & (NB-1));
        int r = (int)(m >> 17);
        unsigned dl = m & 255u;
        stage[lcur[shbase + b] + r] = (unsigned)src[e] | (dl << sbits);
      }
    }
    __syncthreads();
    for(int i = t; i < ce; i += TPB1)
      temp[cb + i] = stage[i];
    __syncthreads();
  }
}

__global__ void k_bscan512(const int* __restrict__ bsize, int E, int* __restrict__ bucket_base){
  __shared__ int s[NB];
  int t = threadIdx.x;
  int v = bsize[t];
  s[t] = v;
  __syncthreads();
  for(int off = 1; off < NB; off <<= 1){
    int add = (t >= off) ? s[t-off] : 0;
    __syncthreads();
    s[t] += add;
    __syncthreads();
  }
  bucket_base[t] = s[t] - v;
  if(t == 0) bucket_base[NB] = E;
}

// bhist[c][b] -> bhistT[b][c]
__global__ void k_transpose(const int* __restrict__ in, int* __restrict__ out,
                            int nchunk, int ncp){
  __shared__ int tl[32][33];
  int bb = blockIdx.x * 32;
  int cb = blockIdx.y * 32;
  int tx = threadIdx.x & 31, ty = threadIdx.x >> 5;
  for(int r = ty; r < 32; r += 8){
    int c = cb + r;
    tl[r][tx] = (c < nchunk) ? in[(size_t)c*NB + bb + tx] : 0;
  }
  __syncthreads();
  for(int r = ty; r < 32; r += 8){
    out[(size_t)(bb + r)*ncp + cb + tx] = tl[tx][r];
  }
}

// per bucket (512 thr): stage bucket edges in LDS (temp read once; chunkoff packs
// st so the copy loop does ZERO global bhistT reads), int-LDS hist + wave-scan
// -> row_start/dinv/ysA, burst-scatter stage -> csr. Fallback: two-pass.
__global__ __launch_bounds__(512)
void k_bucket_build(const unsigned* __restrict__ temp, const int* __restrict__ bhistT,
                    const int* __restrict__ bucket_base,
                    int E, int n, int nchunk, int ncp, int sbits, unsigned smask,
                    int* __restrict__ row_start,
                    float* __restrict__ dinv,
                    const float* __restrict__ x, float* __restrict__ ysA,
                    int* __restrict__ csr){
  __shared__ unsigned stage[MAXB];
  __shared__ int chunkoff[MAXCHUNK+1];   // packed: (st<<14) | off
  __shared__ int hist[MAXW], cur[MAXW];
  __shared__ int ws8[8];
  int b = blockIdx.x;
  int t = threadIdx.x;
  int lo = (int)(((long long)n * b + NB - 1) / NB);
  int hi = (int)(((long long)n * (b+1) + NB - 1) / NB);
  if(hi > n) hi = n;
  int width = hi - lo;
  const int* rowS = bhistT + (size_t)b*ncp;
  const int* rowE = (b < NB-1) ? (bhistT + (size_t)(b+1)*ncp) : (const int*)0;
  bool canstage = (nchunk <= MAXCHUNK);
  if(b == NB-1 && t == 0) row_start[n] = E;

  int run = 0;
  for(int tile = 0; tile < nchunk; tile += 512){
    int c = tile + t;
    int len = 0, st = 0;
    if(c < nchunk){
      st = rowS[c];
      int ce = E - c*CH; if(ce > CH) ce = CH;
      int en = rowE ? rowE[c] : ce;
      len = en - st;
    }
    int incl = block_scan_incl_512(len, ws8);
    if(c < nchunk && canstage) chunkoff[c] = (run + incl - len) | (st << 14);
    run += ws8[7];          // block total (8 waves)
    __syncthreads();        // protect ws8 before next tile / reuse
  }
  int bsz = run;
  if(t == 0 && canstage) chunkoff[nchunk] = bsz;   // sentinel (off only)
  int e0 = bucket_base[b];

  if(t < MAXW) hist[t] = 0;
  __syncthreads();

  if(canstage && bsz <= MAXB){
    int grp = t >> 4, l16 = t & 15;   // 32 groups x 16 lanes (runs ~16 entries)
    for(int c = grp; c < nchunk; c += 32){
      unsigned v0 = (unsigned)chunkoff[c];
      int off = (int)(v0 & 0x3FFFu);
      int st  = (int)(v0 >> 14);
      int len = (int)((unsigned)chunkoff[c+1] & 0x3FFFu) - off;
      int base = c*CH + st;
      for(int i = l16; i < len; i += 16)
        stage[off + i] = temp[base + i];
    }
    __syncthreads();
    for(int i = t; i < bsz; i += 512)
      atomicAdd(&hist[stage[i] >> sbits], 1);      // int LDS atomic: fast
    __syncthreads();
    int v = (t < MAXW) ? hist[t] : 0;
    int incl = block_scan_incl_512(v, ws8);
    int excl = incl - v;
    if(t < MAXW){
      int rs = e0 + excl;
      cur[t] = rs;
      if(t < width){
        int node = lo + t;
        row_start[node] = rs;
        float dv = rsqrtf((float)(v + 1));   // +1 self loop
        dinv[node] = dv;
        ysA[node]  = dv * (10.f * x[node]);
      }
    }
    __syncthreads();
    for(int i = t; i < bsz; i += 512){
      unsigned u = stage[i];
      int pos = atomicAdd(&cur[u >> sbits], 1);
      csr[pos] = (int)(u & smask);
    }
  } else {
    int grp = t >> 4, l16 = t & 15;
    for(int c = grp; c < nchunk; c += 32){
      int cb = c*CH;
      int st = rowS[c];
      int ce = E - cb; if(ce > CH) ce = CH;
      int en = rowE ? rowE[c] : ce;
      for(int i = st + l16; i < en; i += 16)
        atomicAdd(&hist[temp[cb + i] >> sbits], 1);
    }
    __syncthreads();
    int v = (t < MAXW) ? hist[t] : 0;
    int incl = block_scan_incl_512(v, ws8);
    int excl = incl - v;
    if(t < MAXW){
      int rs = e0 + excl;
      cur[t] = rs;
      if(t < width){
        int node = lo + t;
        row_start[node] = rs;
        float dv = rsqrtf((float)(v + 1));
        dinv[node] = dv;
        ysA[node]  = dv * (10.f * x[node]);
      }
    }
    __syncthreads();
    for(int c = grp; c < nchunk; c += 32){
      int cb = c*CH;
      int st = rowS[c];
      int ce = E - cb; if(ce > CH) ce = CH;
      int en = rowE ? rowE[c] : ce;
      for(int i = st + l16; i < en; i += 16){
        unsigned u = temp[cb + i];
        int pos = atomicAdd(&cur[u >> sbits], 1);
        csr[pos] = (int)(u & smask);
      }
    }
  }
}

// ============================ 16-lane-per-node gathers (ILP-4, nt csr loads) ============================
// dg = row_start[node+1] - row_start[node]; csr is a read-once stream -> nontemporal

__global__ void k_gA16(const int* __restrict__ csr, const int* __restrict__ row_start,
                       const float* __restrict__ dinv,
                       const float* __restrict__ ys, const float* __restrict__ W,
                       const float* __restrict__ B, float* __restrict__ y4, int n){
  int g = threadIdx.x >> 4, l = threadIdx.x & 15;
  int node = blockIdx.x*16 + g;
  if(node >= n) return;
  int rs = row_start[node], dg = row_start[node+1] - rs;
  float s = 0.f;
  int j = l;
  for(; j + 48 < dg; j += 64){
    int i0 = __builtin_nontemporal_load(&csr[rs+j]);
    int i1 = __builtin_nontemporal_load(&csr[rs+j+16]);
    int i2 = __builtin_nontemporal_load(&csr[rs+j+32]);
    int i3 = __builtin_nontemporal_load(&csr[rs+j+48]);
    s += ys[i0] + ys[i1] + ys[i2] + ys[i3];
  }
  for(; j < dg; j += 16) s += ys[__builtin_nontemporal_load(&csr[rs+j])];
  #pragma unroll
  for(int m=8; m; m>>=1) s += __shfl_xor(s, m, 16);
  if(l == 0){
    float dv = dinv[node];
    float tt = dv * (ys[node] + s);
    float h0 = fmaxf(tt*W[0]+B[0], 0.f);
    float h1 = fmaxf(tt*W[1]+B[1], 0.f);
    float h2 = fmaxf(tt*W[2]+B[2], 0.f);
    float h3 = fmaxf(tt*W[3]+B[3], 0.f);
    *reinterpret_cast<float4*>(y4 + 4*(size_t)node) = make_float4(dv*h0, dv*h1, dv*h2, dv*h3);
  }
}

__global__ void k_gB16(const int* __restrict__ csr, const int* __restrict__ row_start,
                       const float* __restrict__ dinv,
                       const float* __restrict__ y4, const float* __restrict__ W2,
                       const float* __restrict__ B2, const float* __restrict__ W3,
                       float* __restrict__ ys_out, int n){
  int g = threadIdx.x >> 4, l = threadIdx.x & 15;
  int node = blockIdx.x*16 + g;
  if(node >= n) return;
  int rs = row_start[node], dg = row_start[node+1] - rs;
  float ax=0.f, ay=0.f, az=0.f, aw=0.f;
  int j = l;
  for(; j + 48 < dg; j += 64){
    int i0 = __builtin_nontemporal_load(&csr[rs+j]);
    int i1 = __builtin_nontemporal_load(&csr[rs+j+16]);
    int i2 = __builtin_nontemporal_load(&csr[rs+j+32]);
    int i3 = __builtin_nontemporal_load(&csr[rs+j+48]);
    float4 v0 = *reinterpret_cast<const float4*>(y4 + 4*(size_t)i0);
    float4 v1 = *reinterpret_cast<const float4*>(y4 + 4*(size_t)i1);
    float4 v2 = *reinterpret_cast<const float4*>(y4 + 4*(size_t)i2);
    float4 v3 = *reinterpret_cast<const float4*>(y4 + 4*(size_t)i3);
    ax += v0.x+v1.x+v2.x+v3.x;
    ay += v0.y+v1.y+v2.y+v3.y;
    az += v0.z+v1.z+v2.z+v3.z;
    aw += v0.w+v1.w+v2.w+v3.w;
  }
  for(; j < dg; j += 16){
    int i0 = __builtin_nontemporal_load(&csr[rs+j]);
    float4 v = *reinterpret_cast<const float4*>(y4 + 4*(size_t)i0);
    ax += v.x; ay += v.y; az += v.z; aw += v.w;
  }
  #pragma unroll
  for(int m=8; m; m>>=1){
    ax += __shfl_xor(ax, m, 16);
    ay += __shfl_xor(ay, m, 16);
    az += __shfl_xor(az, m, 16);
    aw += __shfl_xor(aw, m, 16);
  }
  if(l == 0){
    float dv = dinv[node];
    float4 sf = *reinterpret_cast<const float4*>(y4 + 4*(size_t)node);
    float z0 = dv*(ax+sf.x), z1 = dv*(ay+sf.y), z2 = dv*(az+sf.z), z3 = dv*(aw+sf.w);
    float s = 0.f;
    #pragma unroll
    for(int k=0;k<4;k++){
      float gg = B2[k] + z0*W2[0*4+k] + z1*W2[1*4+k] + z2*W2[2*4+k] + z3*W2[3*4+k];
      gg = fmaxf(gg, 0.f);
      s += gg * W3[k];
    }
    ys_out[node] = dv * s;
  }
}

__global__ void k_gC_mid16(const int* __restrict__ csr, const int* __restrict__ row_start,
                           const float* __restrict__ dinv,
                           const float* __restrict__ ys, const float* __restrict__ B3,
                           float* __restrict__ x2, float* __restrict__ ys_out, int n){
  int g = threadIdx.x >> 4, l = threadIdx.x & 15;
  int node = blockIdx.x*16 + g;
  if(node >= n) return;
  int rs = row_start[node], dg = row_start[node+1] - rs;
  float s = 0.f;
  int j = l;
  for(; j + 48 < dg; j += 64){
    int i0 = __builtin_nontemporal_load(&csr[rs+j]);
    int i1 = __builtin_nontemporal_load(&csr[rs+j+16]);
    int i2 = __builtin_nontemporal_load(&csr[rs+j+32]);
    int i3 = __builtin_nontemporal_load(&csr[rs+j+48]);
    s += ys[i0] + ys[i1] + ys[i2] + ys[i3];
  }
  for(; j < dg; j += 16) s += ys[__builtin_nontemporal_load(&csr[rs+j])];
  #pragma unroll
  for(int m=8; m; m>>=1) s += __shfl_xor(s, m, 16);
  if(l == 0){
    float dv = dinv[node];
    float u  = dv * (ys[node] + s) + B3[0];
    float v2 = sinf(10.f * u);
    x2[node] = v2;
    ys_out[node] = dv * v2;
  }
}

__global__ void k_gC_fin16(const int* __restrict__ csr, const int* __restrict__ row_start,
                           const float* __restrict__ dinv,
                           const float* __restrict__ ys, const float* __restrict__ B3,
                           const float* __restrict__ x2, float* __restrict__ out,
                           float* __restrict__ pbuf, int n){
  __shared__ float p2[16], p3[16];
  int g = threadIdx.x >> 4, l = threadIdx.x & 15;
  int node = blockIdx.x*16 + g;
  bool act = node < n;
  float v2 = 0.f, x3 = 0.f;
  if(act){
    int rs = row_start[node], dg = row_start[node+1] - rs;
    float s = 0.f;
    int j = l;
    for(; j + 48 < dg; j += 64){
      int i0 = __builtin_nontemporal_load(&csr[rs+j]);
      int i1 = __builtin_nontemporal_load(&csr[rs+j+16]);
      int i2 = __builtin_nontemporal_load(&csr[rs+j+32]);
      int i3 = __builtin_nontemporal_load(&csr[rs+j+48]);
      s += ys[i0] + ys[i1] + ys[i2] + ys[i3];
    }
    for(; j < dg; j += 16) s += ys[__builtin_nontemporal_load(&csr[rs+j])];
    #pragma unroll
    for(int m=8; m; m>>=1) s += __shfl_xor(s, m, 16);
    if(l == 0){
      x3 = dinv[node] * (ys[node] + s) + B3[0];
      v2 = x2[node];
      *reinterpret_cast<float2*>(out + 2 + 2*(size_t)node) = make_float2(v2, x3);
    }
  }
  if(l == 0){ p2[g] = act ? v2 : 0.f; p3[g] = act ? x3 : 0.f; }
  __syncthreads();
  if(threadIdx.x == 0){
    float a2 = 0.f, a3 = 0.f;
    #pragma unroll
    for(int k=0;k<16;k++){ a2 += p2[k]; a3 += p3[k]; }
    pbuf[2*(size_t)blockIdx.x]   = a2;
    pbuf[2*(size_t)blockIdx.x+1] = a3;
  }
}

__global__ void k_reduce_mean(const float* __restrict__ pbuf, int nb,
                              float* __restrict__ out, float invn){
  float s2 = 0.f, s3 = 0.f;
  for(int i = threadIdx.x; i < nb; i += 1024){
    s2 += pbuf[2*i];
    s3 += pbuf[2*i+1];
  }
  #pragma unroll
  for(int m=32; m; m>>=1){ s2 += __shfl_xor(s2, m, 64); s3 += __shfl_xor(s3, m, 64); }
  __shared__ float a2[16], a3[16];
  int w = threadIdx.x >> 6, lane = threadIdx.x & 63;
  if(lane == 0){ a2[w] = s2; a3[w] = s3; }
  __syncthreads();
  if(threadIdx.x == 0){
    float t2 = 0.f, t3 = 0.f;
    #pragma unroll
    for(int k=0;k<16;k++){ t2 += a2[k]; t3 += a3[k]; }
    out[0] = t2 * invn;
    out[1] = t3 * invn;
  }
}

// ============================ fallback (round-5 path) ============================

__global__ void k_zero8(int* __restrict__ degS, int m){
  int i = blockIdx.x*TPB + threadIdx.x;
  if(i < m) degS[i] = 0;
}

__global__ void k_deg8(const int* __restrict__ dst, int E, int* __restrict__ degS, int n){
  int e = blockIdx.x*TPB + threadIdx.x;
  if(e < E) atomicAdd(&degS[(size_t)(blockIdx.x & (NSHADOW-1))*(size_t)n + dst[e]], 1);
}

__global__ void k_bsum(const int* __restrict__ degS, int n, int* __restrict__ bsum){
  int i = blockIdx.x*TPB + threadIdx.x;
  int v = 0;
  if(i < n){
    #pragma unroll
    for(int s=0;s<NSHADOW;s++) v += degS[(size_t)s*(size_t)n + i];
  }
  #pragma unroll
  for(int off=32; off; off>>=1) v += __shfl_down(v, off, 64);
  __shared__ int ls[4];
  int lane = threadIdx.x & 63, w = threadIdx.x >> 6;
  if(lane == 0) ls[w] = v;
  __syncthreads();
  if(threadIdx.x == 0) bsum[blockIdx.x] = ls[0]+ls[1]+ls[2]+ls[3];
}

__global__ void k_bscan(int* __restrict__ bsum, int nb){
  __shared__ int s[1024];
  int t = threadIdx.x;
  int v = (t < nb) ? bsum[t] : 0;
  s[t] = v;
  __syncthreads();
  for(int off=1; off<1024; off<<=1){
    int add = (t >= off) ? s[t-off] : 0;
    __syncthreads();
    s[t] += add;
    __syncthreads();
  }
  if(t < nb) bsum[t] = s[t] - v;
}

__global__ void k_rowstart2(int* __restrict__ degS, const int* __restrict__ bsum, int n,
                            int* __restrict__ row_start,
                            float* __restrict__ dinv,
                            const float* __restrict__ x, float* __restrict__ ysA){
  __shared__ int s[TPB];
  int i = blockIdx.x*TPB + threadIdx.x;
  int t = threadIdx.x;
  int c[NSHADOW];
  int v = 0;
  if(i < n){
    #pragma unroll
    for(int sh=0;sh<NSHADOW;sh++){ c[sh] = degS[(size_t)sh*(size_t)n + i]; v += c[sh]; }
  }
  s[t] = v;
  __syncthreads();
  for(int off=1; off<TPB; off<<=1){
    int add = (t >= off) ? s[t-off] : 0;
    __syncthreads();
    s[t] += add;
    __syncthreads();
  }
  if(i < n){
    int rs = bsum[blockIdx.x] + s[t] - v;
    row_start[i] = rs;
    if(i == n-1) row_start[n] = rs + v;
    float dv = rsqrtf((float)(v + 1));
    dinv[i] = dv;
    ysA[i]  = dv * (10.f * x[i]);
    int base = rs;
    #pragma unroll
    for(int sh=0;sh<NSHADOW;sh++){ degS[(size_t)sh*(size_t)n + i] = base; base += c[sh]; }
  }
}

__global__ void k_fill_xcd(const int* __restrict__ src, const int* __restrict__ dst,
                           int E, int n, int* __restrict__ cursorS, int* __restrict__ csr){
  int team = blockIdx.x & (NTEAM-1);
  int tr   = blockIdx.x >> 3;
  int lo = (int)(((long long)n * team) >> 3);
  int hi = (int)(((long long)n * (team+1)) >> 3);
  int nchunk = (E + TPB - 1) / TPB;
  for(int ci = tr; ci < nchunk; ci += TEAMS_PER){
    int e = ci*TPB + threadIdx.x;
    if(e < E){
      int d = dst[e];
      if(d >= lo && d < hi){
        int sh = ci & (NSHADOW-1);
        int pos = atomicAdd(&cursorS[(size_t)sh*(size_t)n + d], 1);
        csr[pos] = src[e];
      }
    }
  }
}

// ============================ launch ============================

extern "C" void kernel_launch(void* const* d_in, const int* in_sizes, int n_in,
                              void* d_out, int out_size, void* d_ws, size_t ws_size,
                              hipStream_t stream) {
  const float* x   = (const float*)d_in[0];
  const int*   ei  = (const int*)  d_in[1];
  const float* w11 = (const float*)d_in[2];
  const float* b11 = (const float*)d_in[3];
  const float* w12 = (const float*)d_in[4];
  const float* b12 = (const float*)d_in[5];
  const float* w13 = (const float*)d_in[6];
  const float* b13 = (const float*)d_in[7];
  const float* w21 = (const float*)d_in[8];
  const float* b21 = (const float*)d_in[9];
  const float* w22 = (const float*)d_in[10];
  const float* b22 = (const float*)d_in[11];
  const float* w23 = (const float*)d_in[12];
  const float* b23 = (const float*)d_in[13];
  float* out = (float*)d_out;

  const int n = in_sizes[0];
  const int E = in_sizes[1] / 2;
  const int* src = ei;
  const int* dst = ei + E;

  const int gn   = (n + TPB - 1)/TPB;
  const int gn16 = (n + 15)/16;
  const int ge   = (E + TPB - 1)/TPB;

  float* ws = (float*)d_ws;

  int sbits = 1; while((1 << sbits) < n && sbits < 31) sbits++;
  int maxw  = (n + NB - 1) / NB;
  int dbits = 1; while((1 << dbits) < maxw && dbits < 31) dbits++;
  unsigned smask = (sbits >= 31) ? 0x7FFFFFFFu : ((1u << sbits) - 1u);

  const int nchunk = (E + CH - 1) / CH;
  const int ncp    = ((nchunk + 31) / 32) * 32;

  const size_t need_bucket = ((size_t)10*n + 3072 + (size_t)nchunk*NB + (size_t)NB*ncp
                              + 2*(size_t)E + 64) * 4;
  const size_t need_r5     = ((size_t)18*n + 2048 + (size_t)E + 64) * 4;

  if(ws_size >= need_bucket && n >= NB && maxw <= MAXW && maxw <= 255
     && (sbits + dbits) <= 32 && nchunk <= MAXCHUNK){
    // ---------------- chunk-sorted + staged bucket_build + ILP-4 gathers ----------------
    float*    y4          = ws;                               // 4n (pbuf alias later)
    float*    dinv        = ws + 4*(size_t)n;                 // n
    float*    ysA         = ws + 5*(size_t)n;                 // n
    float*    ysB         = ws + 6*(size_t)n;                 // n
    float*    x2          = ws + 7*(size_t)n;                 // n
    int*      row_start   = (int*)(ws + 8*(size_t)n);         // n+1
    int*      bucket_base = (int*)(ws + 10*(size_t)n);        // NB+1 (pad 2048)
    int*      bsize       = bucket_base + 2048;               // NB (pad 1024)
    int*      bhist       = bsize + 1024;                     // nchunk*NB
    int*      bhistT      = bhist + (size_t)nchunk*NB;        // NB*ncp
    unsigned* temp        = (unsigned*)(bhistT + (size_t)NB*ncp);   // E
    int*      csr         = (int*)(temp + (size_t)E);         // E
    float*    pbuf        = y4;

    int gbuild = nchunk < 8192 ? nchunk : 8192;
    k_zero512    <<<1, 512, 0, stream>>>(bsize);
    k_phase1_sort<<<gbuild, TPB1, 0, stream>>>(src, dst, E, n, nchunk, temp, bhist, bsize, sbits);
    k_bscan512   <<<1, NB, 0, stream>>>(bsize, E, bucket_base);
    {
      dim3 tg(NB/32, (nchunk + 31)/32);
      k_transpose<<<tg, 256, 0, stream>>>(bhist, bhistT, nchunk, ncp);
    }
    k_bucket_build<<<NB, 512, 0, stream>>>(temp, bhistT, bucket_base, E, n, nchunk, ncp,
                                           sbits, smask, row_start, dinv, x, ysA, csr);

    // gcn #1
    k_gA16    <<<gn16, TPB, 0, stream>>>(csr, row_start, dinv, ysA, w11, b11, y4, n);
    k_gB16    <<<gn16, TPB, 0, stream>>>(csr, row_start, dinv, y4, w12, b12, w13, ysB, n);
    k_gC_mid16<<<gn16, TPB, 0, stream>>>(csr, row_start, dinv, ysB, b13, x2, ysA, n);
    // gcn #2
    k_gA16    <<<gn16, TPB, 0, stream>>>(csr, row_start, dinv, ysA, w21, b21, y4, n);
    k_gB16    <<<gn16, TPB, 0, stream>>>(csr, row_start, dinv, y4, w22, b22, w23, ysB, n);
    k_gC_fin16<<<gn16, TPB, 0, stream>>>(csr, row_start, dinv, ysB, b23, x2, out, pbuf, n);
    k_reduce_mean<<<1, 1024, 0, stream>>>(pbuf, gn16, out, 1.f/(float)n);
  } else if(ws_size >= need_r5 && gn <= 1024 && (size_t)E >= (size_t)NSHADOW*(size_t)n){
    // ---------------- round-5 CSR path (fallback) ----------------
    float* y4        = ws;
    float* dinv      = ws + 4*(size_t)n;
    float* ysA       = ws + 5*(size_t)n;
    float* ysB       = ws + 6*(size_t)n;
    float* x2        = ws + 7*(size_t)n;
    int*   row_start = (int*)(ws + 8*(size_t)n);      // n+1
    int*   bsum      = (int*)(ws + 9*(size_t)n + 256);// 1024
    int*   degS      = (int*)(ws + 9*(size_t)n + 1536);// 8n
    int*   csr       = degS + 8*(size_t)n;            // E
    float* pbuf      = y4;

    const int m8 = NSHADOW*n;
    k_zero8    <<<(m8+TPB-1)/TPB, TPB, 0, stream>>>(degS, m8);
    k_deg8     <<<ge, TPB, 0, stream>>>(dst, E, degS, n);
    k_bsum     <<<gn, TPB, 0, stream>>>(degS, n, bsum);
    k_bscan    <<<1, 1024, 0, stream>>>(bsum, gn);
    k_rowstart2<<<gn, TPB, 0, stream>>>(degS, bsum, n, row_start, dinv, x, ysA);
    k_fill_xcd <<<NTEAM*TEAMS_PER, TPB, 0, stream>>>(src, dst, E, n, degS, csr);

    k_gA16    <<<gn16, TPB, 0, stream>>>(csr, row_start, dinv, ysA, w11, b11, y4, n);
    k_gB16    <<<gn16, TPB, 0, stream>>>(csr, row_start, dinv, y4, w12, b12, w13, ysB, n);
    k_gC_mid16<<<gn16, TPB, 0, stream>>>(csr, row_start, dinv, ysB, b13, x2, ysA, n);
    k_gA16    <<<gn16, TPB, 0, stream>>>(csr, row_start, dinv, ysA, w21, b21, y4, n);
    k_gB16    <<<gn16, TPB, 0, stream>>>(csr, row_start, dinv, y4, w22, b22, w23, ysB, n);
    k_gC_fin16<<<gn16, TPB, 0, stream>>>(csr, row_start, dinv, ysB, b23, x2, out, pbuf, n);
    k_reduce_mean<<<1, 1024, 0, stream>>>(pbuf, gn16, out, 1.f/(float)n);
  }
}

// Round 18
// 288.280 us; speedup vs baseline: 1.1531x; 1.1531x over previous
//
#include <hip/hip_runtime.h>
#include <hip/hip_bf16.h>

#define TPB 256
#define TPB1 512        // threads for phase1_sort (1 bucket bin per thread)
#define NB 512          // partition buckets
#define MAXW 256        // max nodes per bucket (ceil(n/NB) <= MAXW)
#define P1K 16          // edges per thread per chunk (TPB1*P1K = 8192)
#define CH (TPB1*P1K)   // 8192 edges per chunk
#define MAXB 13312      // max edges/bucket staged in LDS (52KB); < 2^14 for packing
#define MAXCHUNK 1024
#define NSHADOW 8       // fallback path
#define NTEAM 8
#define TEAMS_PER 256

// inclusive block scan over 512 threads via wave-shfl (2 barriers); ws8 = LDS[8]
__device__ __forceinline__ int block_scan_incl_512(int v, int* ws8){
  int lane = threadIdx.x & 63, wid = threadIdx.x >> 6;
  #pragma unroll
  for(int off=1; off<64; off<<=1){
    int u = __shfl_up(v, off, 64);
    if(lane >= off) v += u;
  }
  if(lane == 63) ws8[wid] = v;
  __syncthreads();
  if(wid == 0){
    int s = (lane < 8) ? ws8[lane] : 0;
    #pragma unroll
    for(int off=1; off<8; off<<=1){
      int u = __shfl_up(s, off, 64);
      if(lane >= off) s += u;
    }
    if(lane < 8) ws8[lane] = s;
  }
  __syncthreads();
  return v + ((wid > 0) ? ws8[wid-1] : 0);
}

// ============================ chunk-sorted build ============================

__global__ void k_zero512(int* __restrict__ bsize){
  bsize[threadIdx.x] = 0;
}

// per chunk: LDS counting sort by dst-bucket, single atomic pass, per-edge state
// packed into ONE register: meta = (r<<17)|(b<<8)|dstLocal. src read at scatter.
__global__ __launch_bounds__(TPB1)
void k_phase1_sort(const int* __restrict__ src, const int* __restrict__ dst,
                   int E, int n, int nchunk,
                   unsigned* __restrict__ temp, int* __restrict__ bhist,
                   int* __restrict__ bsize, int sbits){
  __shared__ int lcur[2*NB];
  __shared__ int ws8[8];
  __shared__ unsigned stage[CH];
  int t = threadIdx.x;
  int wid = t >> 6;
  int shbase = (wid & 1) * NB;
  for(int c = blockIdx.x; c < nchunk; c += gridDim.x){
    int cb = c * CH;
    int ce = E - cb; if(ce > CH) ce = CH;
    lcur[t] = 0; lcur[t + NB] = 0;
    __syncthreads();
    unsigned meta[P1K];
    #pragma unroll
    for(int i = 0; i < P1K; i++){
      int e = cb + i*TPB1 + t;
      if(e < E){
        int d = dst[e];
        int b = (int)(((long long)d * NB) / n);
        int lo = (int)(((long long)n * b + NB - 1) / NB);
        int r = atomicAdd(&lcur[shbase + b], 1);
        meta[i] = ((unsigned)r << 17) | ((unsigned)b << 8) | (unsigned)(d - lo);
      } else meta[i] = 0xFFFFFFFFu;
    }
    __syncthreads();
    int cnt0 = lcur[t], cnt1 = lcur[NB + t];
    int tot = cnt0 + cnt1;
    int incl = block_scan_incl_512(tot, ws8);
    int base = incl - tot;
    bhist[(size_t)c*NB + t] = base;
    if(tot > 0) atomicAdd(&bsize[t], tot);
    lcur[t]      = base;          // shadow-0 base
    lcur[NB + t] = base + cnt0;   // shadow-1 base
    __syncthreads();
    #pragma unroll
    for(int i = 0; i < P1K; i++){
      if(meta[i] != 0xFFFFFFFFu){
        int e = cb + i*TPB1 + t;
        unsigned m = meta[i];
        int b = (int)((m >> 8) & (NB-1));
        int r = (int)(m >> 17);
        unsigned dl = m & 255u;
        stage[lcur[shbase + b] + r] = (unsigned)src[e] | (dl << sbits);
      }
    }
    __syncthreads();
    for(int i = t; i < ce; i += TPB1)
      temp[cb + i] = stage[i];
    __syncthreads();
  }
}

__global__ void k_bscan512(const int* __restrict__ bsize, int E, int* __restrict__ bucket_base){
  __shared__ int s[NB];
  int t = threadIdx.x;
  int v = bsize[t];
  s[t] = v;
  __syncthreads();
  for(int off = 1; off < NB; off <<= 1){
    int add = (t >= off) ? s[t-off] : 0;
    __syncthreads();
    s[t] += add;
    __syncthreads();
  }
  bucket_base[t] = s[t] - v;
  if(t == 0) bucket_base[NB] = E;
}

// bhist[c][b] -> bhistT[b][c]
__global__ void k_transpose(const int* __restrict__ in, int* __restrict__ out,
                            int nchunk, int ncp){
  __shared__ int tl[32][33];
  int bb = blockIdx.x * 32;
  int cb = blockIdx.y * 32;
  int tx = threadIdx.x & 31, ty = threadIdx.x >> 5;
  for(int r = ty; r < 32; r += 8){
    int c = cb + r;
    tl[r][tx] = (c < nchunk) ? in[(size_t)c*NB + bb + tx] : 0;
  }
  __syncthreads();
  for(int r = ty; r < 32; r += 8){
    out[(size_t)(bb + r)*ncp + cb + tx] = tl[tx][r];
  }
}

// per bucket (512 thr): stage bucket edges in LDS (temp read once; chunkoff packs
// st so the copy loop does ZERO global bhistT reads), int-LDS hist + wave-scan
// -> row_start/dinv/ysA, burst-scatter stage -> csr. Fallback: two-pass.
__global__ __launch_bounds__(512)
void k_bucket_build(const unsigned* __restrict__ temp, const int* __restrict__ bhistT,
                    const int* __restrict__ bucket_base,
                    int E, int n, int nchunk, int ncp, int sbits, unsigned smask,
                    int* __restrict__ row_start,
                    float* __restrict__ dinv,
                    const float* __restrict__ x, float* __restrict__ ysA,
                    int* __restrict__ csr){
  __shared__ unsigned stage[MAXB];
  __shared__ int chunkoff[MAXCHUNK+1];   // packed: (st<<14) | off
  __shared__ int hist[MAXW], cur[MAXW];
  __shared__ int ws8[8];
  int b = blockIdx.x;
  int t = threadIdx.x;
  int lo = (int)(((long long)n * b + NB - 1) / NB);
  int hi = (int)(((long long)n * (b+1) + NB - 1) / NB);
  if(hi > n) hi = n;
  int width = hi - lo;
  const int* rowS = bhistT + (size_t)b*ncp;
  const int* rowE = (b < NB-1) ? (bhistT + (size_t)(b+1)*ncp) : (const int*)0;
  bool canstage = (nchunk <= MAXCHUNK);
  if(b == NB-1 && t == 0) row_start[n] = E;

  int run = 0;
  for(int tile = 0; tile < nchunk; tile += 512){
    int c = tile + t;
    int len = 0, st = 0;
    if(c < nchunk){
      st = rowS[c];
      int ce = E - c*CH; if(ce > CH) ce = CH;
      int en = rowE ? rowE[c] : ce;
      len = en - st;
    }
    int incl = block_scan_incl_512(len, ws8);
    if(c < nchunk && canstage) chunkoff[c] = (run + incl - len) | (st << 14);
    run += ws8[7];          // block total (8 waves)
    __syncthreads();        // protect ws8 before next tile / reuse
  }
  int bsz = run;
  if(t == 0 && canstage) chunkoff[nchunk] = bsz;   // sentinel (off only)
  int e0 = bucket_base[b];

  if(t < MAXW) hist[t] = 0;
  __syncthreads();

  if(canstage && bsz <= MAXB){
    int grp = t >> 4, l16 = t & 15;   // 32 groups x 16 lanes (runs ~16 entries)
    for(int c = grp; c < nchunk; c += 32){
      unsigned v0 = (unsigned)chunkoff[c];
      int off = (int)(v0 & 0x3FFFu);
      int st  = (int)(v0 >> 14);
      int len = (int)((unsigned)chunkoff[c+1] & 0x3FFFu) - off;
      int base = c*CH + st;
      for(int i = l16; i < len; i += 16)
        stage[off + i] = temp[base + i];
    }
    __syncthreads();
    for(int i = t; i < bsz; i += 512)
      atomicAdd(&hist[stage[i] >> sbits], 1);      // int LDS atomic: fast
    __syncthreads();
    int v = (t < MAXW) ? hist[t] : 0;
    int incl = block_scan_incl_512(v, ws8);
    int excl = incl - v;
    if(t < MAXW){
      int rs = e0 + excl;
      cur[t] = rs;
      if(t < width){
        int node = lo + t;
        row_start[node] = rs;
        float dv = rsqrtf((float)(v + 1));   // +1 self loop
        dinv[node] = dv;
        ysA[node]  = dv * (10.f * x[node]);
      }
    }
    __syncthreads();
    for(int i = t; i < bsz; i += 512){
      unsigned u = stage[i];
      int pos = atomicAdd(&cur[u >> sbits], 1);
      csr[pos] = (int)(u & smask);
    }
  } else {
    int grp = t >> 4, l16 = t & 15;
    for(int c = grp; c < nchunk; c += 32){
      int cb = c*CH;
      int st = rowS[c];
      int ce = E - cb; if(ce > CH) ce = CH;
      int en = rowE ? rowE[c] : ce;
      for(int i = st + l16; i < en; i += 16)
        atomicAdd(&hist[temp[cb + i] >> sbits], 1);
    }
    __syncthreads();
    int v = (t < MAXW) ? hist[t] : 0;
    int incl = block_scan_incl_512(v, ws8);
    int excl = incl - v;
    if(t < MAXW){
      int rs = e0 + excl;
      cur[t] = rs;
      if(t < width){
        int node = lo + t;
        row_start[node] = rs;
        float dv = rsqrtf((float)(v + 1));
        dinv[node] = dv;
        ysA[node]  = dv * (10.f * x[node]);
      }
    }
    __syncthreads();
    for(int c = grp; c < nchunk; c += 32){
      int cb = c*CH;
      int st = rowS[c];
      int ce = E - cb; if(ce > CH) ce = CH;
      int en = rowE ? rowE[c] : ce;
      for(int i = st + l16; i < en; i += 16){
        unsigned u = temp[cb + i];
        int pos = atomicAdd(&cur[u >> sbits], 1);
        csr[pos] = (int)(u & smask);
      }
    }
  }
}

// ============================ 16-lane-per-node gathers (ILP-4, plain loads) ============================
// dg = row_start[node+1] - row_start[node]

__global__ void k_gA16(const int* __restrict__ csr, const int* __restrict__ row_start,
                       const float* __restrict__ dinv,
                       const float* __restrict__ ys, const float* __restrict__ W,
                       const float* __restrict__ B, float* __restrict__ y4, int n){
  int g = threadIdx.x >> 4, l = threadIdx.x & 15;
  int node = blockIdx.x*16 + g;
  if(node >= n) return;
  int rs = row_start[node], dg = row_start[node+1] - rs;
  float s = 0.f;
  int j = l;
  for(; j + 48 < dg; j += 64){
    int i0 = csr[rs+j], i1 = csr[rs+j+16], i2 = csr[rs+j+32], i3 = csr[rs+j+48];
    s += ys[i0] + ys[i1] + ys[i2] + ys[i3];
  }
  for(; j < dg; j += 16) s += ys[csr[rs+j]];
  #pragma unroll
  for(int m=8; m; m>>=1) s += __shfl_xor(s, m, 16);
  if(l == 0){
    float dv = dinv[node];
    float tt = dv * (ys[node] + s);
    float h0 = fmaxf(tt*W[0]+B[0], 0.f);
    float h1 = fmaxf(tt*W[1]+B[1], 0.f);
    float h2 = fmaxf(tt*W[2]+B[2], 0.f);
    float h3 = fmaxf(tt*W[3]+B[3], 0.f);
    *reinterpret_cast<float4*>(y4 + 4*(size_t)node) = make_float4(dv*h0, dv*h1, dv*h2, dv*h3);
  }
}

__global__ void k_gB16(const int* __restrict__ csr, const int* __restrict__ row_start,
                       const float* __restrict__ dinv,
                       const float* __restrict__ y4, const float* __restrict__ W2,
                       const float* __restrict__ B2, const float* __restrict__ W3,
                       float* __restrict__ ys_out, int n){
  int g = threadIdx.x >> 4, l = threadIdx.x & 15;
  int node = blockIdx.x*16 + g;
  if(node >= n) return;
  int rs = row_start[node], dg = row_start[node+1] - rs;
  float ax=0.f, ay=0.f, az=0.f, aw=0.f;
  int j = l;
  for(; j + 48 < dg; j += 64){
    int i0 = csr[rs+j], i1 = csr[rs+j+16], i2 = csr[rs+j+32], i3 = csr[rs+j+48];
    float4 v0 = *reinterpret_cast<const float4*>(y4 + 4*(size_t)i0);
    float4 v1 = *reinterpret_cast<const float4*>(y4 + 4*(size_t)i1);
    float4 v2 = *reinterpret_cast<const float4*>(y4 + 4*(size_t)i2);
    float4 v3 = *reinterpret_cast<const float4*>(y4 + 4*(size_t)i3);
    ax += v0.x+v1.x+v2.x+v3.x;
    ay += v0.y+v1.y+v2.y+v3.y;
    az += v0.z+v1.z+v2.z+v3.z;
    aw += v0.w+v1.w+v2.w+v3.w;
  }
  for(; j < dg; j += 16){
    float4 v = *reinterpret_cast<const float4*>(y4 + 4*(size_t)csr[rs+j]);
    ax += v.x; ay += v.y; az += v.z; aw += v.w;
  }
  #pragma unroll
  for(int m=8; m; m>>=1){
    ax += __shfl_xor(ax, m, 16);
    ay += __shfl_xor(ay, m, 16);
    az += __shfl_xor(az, m, 16);
    aw += __shfl_xor(aw, m, 16);
  }
  if(l == 0){
    float dv = dinv[node];
    float4 sf = *reinterpret_cast<const float4*>(y4 + 4*(size_t)node);
    float z0 = dv*(ax+sf.x), z1 = dv*(ay+sf.y), z2 = dv*(az+sf.z), z3 = dv*(aw+sf.w);
    float s = 0.f;
    #pragma unroll
    for(int k=0;k<4;k++){
      float gg = B2[k] + z0*W2[0*4+k] + z1*W2[1*4+k] + z2*W2[2*4+k] + z3*W2[3*4+k];
      gg = fmaxf(gg, 0.f);
      s += gg * W3[k];
    }
    ys_out[node] = dv * s;
  }
}

__global__ void k_gC_mid16(const int* __restrict__ csr, const int* __restrict__ row_start,
                           const float* __restrict__ dinv,
                           const float* __restrict__ ys, const float* __restrict__ B3,
                           float* __restrict__ x2, float* __restrict__ ys_out, int n){
  int g = threadIdx.x >> 4, l = threadIdx.x & 15;
  int node = blockIdx.x*16 + g;
  if(node >= n) return;
  int rs = row_start[node], dg = row_start[node+1] - rs;
  float s = 0.f;
  int j = l;
  for(; j + 48 < dg; j += 64){
    int i0 = csr[rs+j], i1 = csr[rs+j+16], i2 = csr[rs+j+32], i3 = csr[rs+j+48];
    s += ys[i0] + ys[i1] + ys[i2] + ys[i3];
  }
  for(; j < dg; j += 16) s += ys[csr[rs+j]];
  #pragma unroll
  for(int m=8; m; m>>=1) s += __shfl_xor(s, m, 16);
  if(l == 0){
    float dv = dinv[node];
    float u  = dv * (ys[node] + s) + B3[0];
    float v2 = sinf(10.f * u);
    x2[node] = v2;
    ys_out[node] = dv * v2;
  }
}

__global__ void k_gC_fin16(const int* __restrict__ csr, const int* __restrict__ row_start,
                           const float* __restrict__ dinv,
                           const float* __restrict__ ys, const float* __restrict__ B3,
                           const float* __restrict__ x2, float* __restrict__ out,
                           float* __restrict__ pbuf, int n){
  __shared__ float p2[16], p3[16];
  int g = threadIdx.x >> 4, l = threadIdx.x & 15;
  int node = blockIdx.x*16 + g;
  bool act = node < n;
  float v2 = 0.f, x3 = 0.f;
  if(act){
    int rs = row_start[node], dg = row_start[node+1] - rs;
    float s = 0.f;
    int j = l;
    for(; j + 48 < dg; j += 64){
      int i0 = csr[rs+j], i1 = csr[rs+j+16], i2 = csr[rs+j+32], i3 = csr[rs+j+48];
      s += ys[i0] + ys[i1] + ys[i2] + ys[i3];
    }
    for(; j < dg; j += 16) s += ys[csr[rs+j]];
    #pragma unroll
    for(int m=8; m; m>>=1) s += __shfl_xor(s, m, 16);
    if(l == 0){
      x3 = dinv[node] * (ys[node] + s) + B3[0];
      v2 = x2[node];
      *reinterpret_cast<float2*>(out + 2 + 2*(size_t)node) = make_float2(v2, x3);
    }
  }
  if(l == 0){ p2[g] = act ? v2 : 0.f; p3[g] = act ? x3 : 0.f; }
  __syncthreads();
  if(threadIdx.x == 0){
    float a2 = 0.f, a3 = 0.f;
    #pragma unroll
    for(int k=0;k<16;k++){ a2 += p2[k]; a3 += p3[k]; }
    pbuf[2*(size_t)blockIdx.x]   = a2;
    pbuf[2*(size_t)blockIdx.x+1] = a3;
  }
}

__global__ void k_reduce_mean(const float* __restrict__ pbuf, int nb,
                              float* __restrict__ out, float invn){
  float s2 = 0.f, s3 = 0.f;
  for(int i = threadIdx.x; i < nb; i += 1024){
    s2 += pbuf[2*i];
    s3 += pbuf[2*i+1];
  }
  #pragma unroll
  for(int m=32; m; m>>=1){ s2 += __shfl_xor(s2, m, 64); s3 += __shfl_xor(s3, m, 64); }
  __shared__ float a2[16], a3[16];
  int w = threadIdx.x >> 6, lane = threadIdx.x & 63;
  if(lane == 0){ a2[w] = s2; a3[w] = s3; }
  __syncthreads();
  if(threadIdx.x == 0){
    float t2 = 0.f, t3 = 0.f;
    #pragma unroll
    for(int k=0;k<16;k++){ t2 += a2[k]; t3 += a3[k]; }
    out[0] = t2 * invn;
    out[1] = t3 * invn;
  }
}

// ============================ fallback (round-5 path) ============================

__global__ void k_zero8(int* __restrict__ degS, int m){
  int i = blockIdx.x*TPB + threadIdx.x;
  if(i < m) degS[i] = 0;
}

__global__ void k_deg8(const int* __restrict__ dst, int E, int* __restrict__ degS, int n){
  int e = blockIdx.x*TPB + threadIdx.x;
  if(e < E) atomicAdd(&degS[(size_t)(blockIdx.x & (NSHADOW-1))*(size_t)n + dst[e]], 1);
}

__global__ void k_bsum(const int* __restrict__ degS, int n, int* __restrict__ bsum){
  int i = blockIdx.x*TPB + threadIdx.x;
  int v = 0;
  if(i < n){
    #pragma unroll
    for(int s=0;s<NSHADOW;s++) v += degS[(size_t)s*(size_t)n + i];
  }
  #pragma unroll
  for(int off=32; off; off>>=1) v += __shfl_down(v, off, 64);
  __shared__ int ls[4];
  int lane = threadIdx.x & 63, w = threadIdx.x >> 6;
  if(lane == 0) ls[w] = v;
  __syncthreads();
  if(threadIdx.x == 0) bsum[blockIdx.x] = ls[0]+ls[1]+ls[2]+ls[3];
}

__global__ void k_bscan(int* __restrict__ bsum, int nb){
  __shared__ int s[1024];
  int t = threadIdx.x;
  int v = (t < nb) ? bsum[t] : 0;
  s[t] = v;
  __syncthreads();
  for(int off=1; off<1024; off<<=1){
    int add = (t >= off) ? s[t-off] : 0;
    __syncthreads();
    s[t] += add;
    __syncthreads();
  }
  if(t < nb) bsum[t] = s[t] - v;
}

__global__ void k_rowstart2(int* __restrict__ degS, const int* __restrict__ bsum, int n,
                            int* __restrict__ row_start,
                            float* __restrict__ dinv,
                            const float* __restrict__ x, float* __restrict__ ysA){
  __shared__ int s[TPB];
  int i = blockIdx.x*TPB + threadIdx.x;
  int t = threadIdx.x;
  int c[NSHADOW];
  int v = 0;
  if(i < n){
    #pragma unroll
    for(int sh=0;sh<NSHADOW;sh++){ c[sh] = degS[(size_t)sh*(size_t)n + i]; v += c[sh]; }
  }
  s[t] = v;
  __syncthreads();
  for(int off=1; off<TPB; off<<=1){
    int add = (t >= off) ? s[t-off] : 0;
    __syncthreads();
    s[t] += add;
    __syncthreads();
  }
  if(i < n){
    int rs = bsum[blockIdx.x] + s[t] - v;
    row_start[i] = rs;
    if(i == n-1) row_start[n] = rs + v;
    float dv = rsqrtf((float)(v + 1));
    dinv[i] = dv;
    ysA[i]  = dv * (10.f * x[i]);
    int base = rs;
    #pragma unroll
    for(int sh=0;sh<NSHADOW;sh++){ degS[(size_t)sh*(size_t)n + i] = base; base += c[sh]; }
  }
}

__global__ void k_fill_xcd(const int* __restrict__ src, const int* __restrict__ dst,
                           int E, int n, int* __restrict__ cursorS, int* __restrict__ csr){
  int team = blockIdx.x & (NTEAM-1);
  int tr   = blockIdx.x >> 3;
  int lo = (int)(((long long)n * team) >> 3);
  int hi = (int)(((long long)n * (team+1)) >> 3);
  int nchunk = (E + TPB - 1) / TPB;
  for(int ci = tr; ci < nchunk; ci += TEAMS_PER){
    int e = ci*TPB + threadIdx.x;
    if(e < E){
      int d = dst[e];
      if(d >= lo && d < hi){
        int sh = ci & (NSHADOW-1);
        int pos = atomicAdd(&cursorS[(size_t)sh*(size_t)n + d], 1);
        csr[pos] = src[e];
      }
    }
  }
}

// ============================ launch ============================

extern "C" void kernel_launch(void* const* d_in, const int* in_sizes, int n_in,
                              void* d_out, int out_size, void* d_ws, size_t ws_size,
                              hipStream_t stream) {
  const float* x   = (const float*)d_in[0];
  const int*   ei  = (const int*)  d_in[1];
  const float* w11 = (const float*)d_in[2];
  const float* b11 = (const float*)d_in[3];
  const float* w12 = (const float*)d_in[4];
  const float* b12 = (const float*)d_in[5];
  const float* w13 = (const float*)d_in[6];
  const float* b13 = (const float*)d_in[7];
  const float* w21 = (const float*)d_in[8];
  const float* b21 = (const float*)d_in[9];
  const float* w22 = (const float*)d_in[10];
  const float* b22 = (const float*)d_in[11];
  const float* w23 = (const float*)d_in[12];
  const float* b23 = (const float*)d_in[13];
  float* out = (float*)d_out;

  const int n = in_sizes[0];
  const int E = in_sizes[1] / 2;
  const int* src = ei;
  const int* dst = ei + E;

  const int gn   = (n + TPB - 1)/TPB;
  const int gn16 = (n + 15)/16;
  const int ge   = (E + TPB - 1)/TPB;

  float* ws = (float*)d_ws;

  int sbits = 1; while((1 << sbits) < n && sbits < 31) sbits++;
  int maxw  = (n + NB - 1) / NB;
  int dbits = 1; while((1 << dbits) < maxw && dbits < 31) dbits++;
  unsigned smask = (sbits >= 31) ? 0x7FFFFFFFu : ((1u << sbits) - 1u);

  const int nchunk = (E + CH - 1) / CH;
  const int ncp    = ((nchunk + 31) / 32) * 32;

  const size_t need_bucket = ((size_t)10*n + 3072 + (size_t)nchunk*NB + (size_t)NB*ncp
                              + 2*(size_t)E + 64) * 4;
  const size_t need_r5     = ((size_t)18*n + 2048 + (size_t)E + 64) * 4;

  if(ws_size >= need_bucket && n >= NB && maxw <= MAXW && maxw <= 255
     && (sbits + dbits) <= 32 && nchunk <= MAXCHUNK){
    // ---------------- chunk-sorted + staged bucket_build + ILP-4 gathers ----------------
    float*    y4          = ws;                               // 4n (pbuf alias later)
    float*    dinv        = ws + 4*(size_t)n;                 // n
    float*    ysA         = ws + 5*(size_t)n;                 // n
    float*    ysB         = ws + 6*(size_t)n;                 // n
    float*    x2          = ws + 7*(size_t)n;                 // n
    int*      row_start   = (int*)(ws + 8*(size_t)n);         // n+1
    int*      bucket_base = (int*)(ws + 10*(size_t)n);        // NB+1 (pad 2048)
    int*      bsize       = bucket_base + 2048;               // NB (pad 1024)
    int*      bhist       = bsize + 1024;                     // nchunk*NB
    int*      bhistT      = bhist + (size_t)nchunk*NB;        // NB*ncp
    unsigned* temp        = (unsigned*)(bhistT + (size_t)NB*ncp);   // E
    int*      csr         = (int*)(temp + (size_t)E);         // E
    float*    pbuf        = y4;

    int gbuild = nchunk < 8192 ? nchunk : 8192;
    k_zero512    <<<1, 512, 0, stream>>>(bsize);
    k_phase1_sort<<<gbuild, TPB1, 0, stream>>>(src, dst, E, n, nchunk, temp, bhist, bsize, sbits);
    k_bscan512   <<<1, NB, 0, stream>>>(bsize, E, bucket_base);
    {
      dim3 tg(NB/32, (nchunk + 31)/32);
      k_transpose<<<tg, 256, 0, stream>>>(bhist, bhistT, nchunk, ncp);
    }
    k_bucket_build<<<NB, 512, 0, stream>>>(temp, bhistT, bucket_base, E, n, nchunk, ncp,
                                           sbits, smask, row_start, dinv, x, ysA, csr);

    // gcn #1
    k_gA16    <<<gn16, TPB, 0, stream>>>(csr, row_start, dinv, ysA, w11, b11, y4, n);
    k_gB16    <<<gn16, TPB, 0, stream>>>(csr, row_start, dinv, y4, w12, b12, w13, ysB, n);
    k_gC_mid16<<<gn16, TPB, 0, stream>>>(csr, row_start, dinv, ysB, b13, x2, ysA, n);
    // gcn #2
    k_gA16    <<<gn16, TPB, 0, stream>>>(csr, row_start, dinv, ysA, w21, b21, y4, n);
    k_gB16    <<<gn16, TPB, 0, stream>>>(csr, row_start, dinv, y4, w22, b22, w23, ysB, n);
    k_gC_fin16<<<gn16, TPB, 0, stream>>>(csr, row_start, dinv, ysB, b23, x2, out, pbuf, n);
    k_reduce_mean<<<1, 1024, 0, stream>>>(pbuf, gn16, out, 1.f/(float)n);
  } else if(ws_size >= need_r5 && gn <= 1024 && (size_t)E >= (size_t)NSHADOW*(size_t)n){
    // ---------------- round-5 CSR path (fallback) ----------------
    float* y4        = ws;
    float* dinv      = ws + 4*(size_t)n;
    float* ysA       = ws + 5*(size_t)n;
    float* ysB       = ws + 6*(size_t)n;
    float* x2        = ws + 7*(size_t)n;
    int*   row_start = (int*)(ws + 8*(size_t)n);      // n+1
    int*   bsum      = (int*)(ws + 9*(size_t)n + 256);// 1024
    int*   degS      = (int*)(ws + 9*(size_t)n + 1536);// 8n
    int*   csr       = degS + 8*(size_t)n;            // E
    float* pbuf      = y4;

    const int m8 = NSHADOW*n;
    k_zero8    <<<(m8+TPB-1)/TPB, TPB, 0, stream>>>(degS, m8);
    k_deg8     <<<ge, TPB, 0, stream>>>(dst, E, degS, n);
    k_bsum     <<<gn, TPB, 0, stream>>>(degS, n, bsum);
    k_bscan    <<<1, 1024, 0, stream>>>(bsum, gn);
    k_rowstart2<<<gn, TPB, 0, stream>>>(degS, bsum, n, row_start, dinv, x, ysA);
    k_fill_xcd <<<NTEAM*TEAMS_PER, TPB, 0, stream>>>(src, dst, E, n, degS, csr);

    k_gA16    <<<gn16, TPB, 0, stream>>>(csr, row_start, dinv, ysA, w11, b11, y4, n);
    k_gB16    <<<gn16, TPB, 0, stream>>>(csr, row_start, dinv, y4, w12, b12, w13, ysB, n);
    k_gC_mid16<<<gn16, TPB, 0, stream>>>(csr, row_start, dinv, ysB, b13, x2, ysA, n);
    k_gA16    <<<gn16, TPB, 0, stream>>>(csr, row_start, dinv, ysA, w21, b21, y4, n);
    k_gB16    <<<gn16, TPB, 0, stream>>>(csr, row_start, dinv, y4, w22, b22, w23, ysB, n);
    k_gC_fin16<<<gn16, TPB, 0, stream>>>(csr, row_start, dinv, ysB, b23, x2, out, pbuf, n);
    k_reduce_mean<<<1, 1024, 0, stream>>>(pbuf, gn16, out, 1.f/(float)n);
  }
}